// Round 22
// baseline (86.376 us; speedup 1.0000x reference)
//
#include <hip/hip_runtime.h>
#include <math.h>

#define NB 4096   // batch
#define NS 64     // seq
#define NF 8      // feat
#define ND 64     // d_model
#define KL 512    // GEMM K = NS*NF (rank-8 trick)
#define NK 16     // top-k

typedef _Float16 half8 __attribute__((ext_vector_type(8)));
typedef float    f32x4 __attribute__((ext_vector_type(4)));

#define GLD16(src, dst) \
  __builtin_amdgcn_global_load_lds((const __attribute__((address_space(1))) void*)(src), \
                                   (__attribute__((address_space(3))) void*)(dst), 16, 0, 0)

#define WAITVM(N) asm volatile("s_waitcnt vmcnt(" #N ")" ::: "memory")

// packed candidate key: top-20 bits of sortable f32 | (4095 - col).
// u32 max == exact (value, lowest-col) order; key 0 = -inf sentinel.
__device__ __forceinline__ unsigned f32key(float v, int col) {
    const unsigned u = __float_as_uint(v);
    const unsigned s = ((int)u < 0) ? ~u : (u | 0x80000000u);
    return (s & 0xFFFFF000u) | (unsigned)(4095 - col);
}

// top-2 maintenance (M1 >= M2 invariant)
#define UPD2(M1, M2, K) { const unsigned k_ = (K); \
    if (k_ > M1) { M2 = M1; M1 = k_; } else if (k_ > M2) M2 = k_; }

// ---------------- block reduce helper ----------------
__device__ __forceinline__ float blk_reduce(float v, float* red) {
    #pragma unroll
    for (int o = 32; o > 0; o >>= 1) v += __shfl_down(v, o, 64);
    const int t = threadIdx.x;
    __syncthreads();
    if ((t & 63) == 0) red[t >> 6] = v;
    __syncthreads();
    float r = 0.f;
    if (t == 0) r = red[0] + red[1] + red[2] + red[3];
    return r;
}

// ---- prep (consts fused): X16=fp16(x), Y16=fp16(x@G), proj=x@M+c8,
//      r[b]=sum_s x.u, term1 partial -> p1[bid]; block 0 zeroes the done-counter ----
__global__ __launch_bounds__(256) void prep_kernel(
    const float* __restrict__ x, const float* __restrict__ Wemb,
    const float* __restrict__ bemb, const float* __restrict__ Wp,
    const float* __restrict__ bp,
    _Float16* __restrict__ X16, _Float16* __restrict__ Y16,
    float* __restrict__ proj, float* __restrict__ r, double* __restrict__ p1,
    unsigned* __restrict__ cnt)
{
    __shared__ float sWe[512], sWp[512], sbe[64], sbp[8];
    __shared__ float sG[64], sM[64], su[8], sc[8];
    __shared__ float red[4];
    const int t = threadIdx.x, lane = t & 63, w = t >> 6;
    if (blockIdx.x == 0 && t == 0) *cnt = 0u;       // reset done-counter each call
    sWe[t] = Wemb[t]; sWe[t + 256] = Wemb[t + 256];
    sWp[t] = Wp[t];   sWp[t + 256] = Wp[t + 256];
    if (t < 64) sbe[t] = bemb[t];
    if (t < 8)  sbp[t] = bp[t];
    __syncthreads();
    if (t < 64) {               // G = We@We^T, M = We@Wp  (8x8 each)
        const int f = t >> 3, f2 = t & 7;
        float g = 0.f, m = 0.f;
        #pragma unroll
        for (int d = 0; d < ND; ++d) {
            g += sWe[f * ND + d] * sWe[f2 * ND + d];
            m += sWe[f * ND + d] * sWp[d * NF + f2];
        }
        sG[t] = g; sM[t] = m;
    }
    if (t < 8) {                // u = We@be, c8 = be@Wp + bp
        float uu = 0.f, cc = 0.f;
        #pragma unroll
        for (int d = 0; d < ND; ++d) {
            uu += sWe[t * ND + d] * sbe[d];
            cc += sbe[d] * sWp[d * NF + t];
        }
        su[t] = uu; sc[t] = cc + sbp[t];
    }
    __syncthreads();

    const int b = blockIdx.x * 4 + w;
    const size_t base = (size_t)b * KL + lane * 8;
    const f32x4 x0 = *(const f32x4*)&x[base];
    const f32x4 x1 = *(const f32x4*)&x[base + 4];
    float xv[8] = {x0[0], x0[1], x0[2], x0[3], x1[0], x1[1], x1[2], x1[3]};
    float yv[8], pv[8];
    #pragma unroll
    for (int f2 = 0; f2 < 8; ++f2) { yv[f2] = 0.f; pv[f2] = sc[f2]; }
    #pragma unroll
    for (int f = 0; f < 8; ++f)
        #pragma unroll
        for (int f2 = 0; f2 < 8; ++f2) {
            yv[f2] += xv[f] * sG[f * 8 + f2];
            pv[f2] += xv[f] * sM[f * 8 + f2];
        }
    half8 hx, hy;
    #pragma unroll
    for (int j = 0; j < 8; ++j) { hx[j] = (_Float16)xv[j]; hy[j] = (_Float16)yv[j]; }
    *(half8*)&X16[base] = hx;
    *(half8*)&Y16[base] = hy;
    *(f32x4*)&proj[base] = (f32x4){pv[0], pv[1], pv[2], pv[3]};
    *(f32x4*)&proj[base + 4] = (f32x4){pv[4], pv[5], pv[6], pv[7]};
    float rv = 0.f;
    #pragma unroll
    for (int f = 0; f < 8; ++f) rv += xv[f] * su[f];
    #pragma unroll
    for (int o = 32; o > 0; o >>= 1) rv += __shfl_down(rv, o, 64);
    if (lane == 0) r[b] = rv;
    float s1 = 0.f;
    #pragma unroll
    for (int j = 0; j < 8; ++j) { const float d = pv[j] - xv[j]; s1 += d * d; }
    const float tot = blk_reduce(s1, red);
    if (t == 0) p1[blockIdx.x] = (double)tot;
}

// ---- dot = X @ Y^T (K=512) fp16 MFMA, 128x64 tiles (2048 blocks),
//      BK=64 phases: 8 phases x (6 GLD16 + 16 MFMA + 1 barrier), 3-buf depth-2 ----
__global__ __launch_bounds__(256) void attn_gemm_kernel(
    const _Float16* __restrict__ Xf, const _Float16* __restrict__ Yf,
    const float* __restrict__ rvec, unsigned* __restrict__ cand)
{
    // 3 bufs x (A 128x64 = 16 KB + B 64x64 = 8 KB) = 72 KB; dp overlays (17.4 KB)
    __shared__ __align__(16) char smem_raw[73728];
    _Float16* smem = (_Float16*)smem_raw;

    const int t = threadIdx.x;
    const int lane = t & 63, wid = t >> 6;

    // 2D XCD map: each XCD owns an 8(it) x 32(jt) rectangle -> ~3 MB L2 working set
    const int xcd = blockIdx.x & 7, q = blockIdx.x >> 3;
    const int it = (xcd >> 1) * 8 + (q >> 5);       // 0..31
    const int jt = (xcd & 1) * 32 + (q & 31);       // 0..63
    const int i0 = it * 128, j0 = jt * 64;

    f32x4 acc[2][4];
    #pragma unroll
    for (int m = 0; m < 2; ++m)
        #pragma unroll
        for (int n = 0; n < 4; ++n) acc[m][n] = (f32x4){0.f, 0.f, 0.f, 0.f};

    const int lrow = lane & 15, g = lane >> 4;

    // staging: per stage 1536 chunks (A 1024: row=id>>3,c=id&7; B 512) ; 6/thread
    // source-side 3-bit XOR swizzle: global chunk = c ^ (row&7)
    const int idA0 = t,       rA0 = idA0 >> 3, cA0s = ((idA0 & 7) ^ (rA0 & 7)) * 8;
    const int idA1 = t + 256, rA1 = idA1 >> 3, cA1s = ((idA1 & 7) ^ (rA1 & 7)) * 8;
    const int idA2 = t + 512, rA2 = idA2 >> 3, cA2s = ((idA2 & 7) ^ (rA2 & 7)) * 8;
    const int idA3 = t + 768, rA3 = idA3 >> 3, cA3s = ((idA3 & 7) ^ (rA3 & 7)) * 8;
    const int idB0 = t,       rB0 = idB0 >> 3, cB0s = ((idB0 & 7) ^ (rB0 & 7)) * 8;
    const int idB1 = t + 256, rB1 = idB1 >> 3, cB1s = ((idB1 & 7) ^ (rB1 & 7)) * 8;
    const _Float16* pA0 = Xf + (size_t)(i0 + rA0) * KL + cA0s;
    const _Float16* pA1 = Xf + (size_t)(i0 + rA1) * KL + cA1s;
    const _Float16* pA2 = Xf + (size_t)(i0 + rA2) * KL + cA2s;
    const _Float16* pA3 = Xf + (size_t)(i0 + rA3) * KL + cA3s;
    const _Float16* pB0 = Yf + (size_t)(j0 + rB0) * KL + cB0s;
    const _Float16* pB1 = Yf + (size_t)(j0 + rB1) * KL + cB1s;
    _Float16* dA0 = smem + idA0 * 8;
    _Float16* dA1 = smem + idA1 * 8;
    _Float16* dA2 = smem + idA2 * 8;
    _Float16* dA3 = smem + idA3 * 8;
    _Float16* dB0 = smem + 8192 + idB0 * 8;   // B at +16 KB (8192 halves)
    _Float16* dB1 = smem + 8192 + idB1 * 8;

#define STG(BUF, KH) { \
    GLD16(pA0 + (KH), dA0 + (BUF) * 12288); \
    GLD16(pA1 + (KH), dA1 + (BUF) * 12288); \
    GLD16(pA2 + (KH), dA2 + (BUF) * 12288); \
    GLD16(pA3 + (KH), dA3 + (BUF) * 12288); \
    GLD16(pB0 + (KH), dB0 + (BUF) * 12288); \
    GLD16(pB1 + (KH), dB1 + (BUF) * 12288); }

    // read side: row stride 64 halves; chunk = (ks*4+g) ^ (lrow&7)
    const int swz0 = (g ^ (lrow & 7)) * 8;          // ks=0
    const int swz1 = ((4 + g) ^ (lrow & 7)) * 8;    // ks=1
    const int roA = (wid * 32 + lrow) * 64;         // wave's 32-row quarter
    const int roB = lrow * 64;

#define COMPUTE(BUF) { \
    const _Float16* sA = smem + (BUF) * 12288 + roA; \
    const _Float16* sB = smem + (BUF) * 12288 + 8192 + roB; \
    _Pragma("unroll") \
    for (int ks = 0; ks < 2; ++ks) { \
        const int sw = ks ? swz1 : swz0; \
        half8 fa[2], fb[4]; \
        _Pragma("unroll") \
        for (int m = 0; m < 2; ++m) fa[m] = *(const half8*)&sA[m * 1024 + sw]; \
        _Pragma("unroll") \
        for (int n = 0; n < 4; ++n) fb[n] = *(const half8*)&sB[n * 1024 + sw]; \
        _Pragma("unroll") \
        for (int m = 0; m < 2; ++m) \
            _Pragma("unroll") \
            for (int n = 0; n < 4; ++n) \
                acc[m][n] = __builtin_amdgcn_mfma_f32_16x16x32_f16(fa[m], fb[n], acc[m][n], 0, 0, 0); \
    } }

#define BUMP(NH) { pA0 += NH; pA1 += NH; pA2 += NH; pA3 += NH; pB0 += NH; pB1 += NH; }

    // prologue: stages 0 (k=0), 1 (k=64)
    STG(0, 0); STG(1, 64);
    BUMP(128)
    // phases 0..5: wait own stage, barrier, stage ph+2, compute
    #pragma unroll 1
    for (int io = 0; io < 2; ++io) {
        WAITVM(6); __builtin_amdgcn_s_barrier(); STG(2, 0);   COMPUTE(0);
        WAITVM(6); __builtin_amdgcn_s_barrier(); STG(0, 64);  COMPUTE(1);
        WAITVM(6); __builtin_amdgcn_s_barrier(); STG(1, 128); COMPUTE(2);
        BUMP(192)
    }
    // phases 6,7
    WAITVM(6); __builtin_amdgcn_s_barrier(); COMPUTE(0);
    WAITVM(0); __builtin_amdgcn_s_barrier(); COMPUTE(1);
#undef STG
#undef COMPUTE
#undef BUMP

    // r[j] for this lane's 4 cols (one per n-frag)
    float rj[4];
    #pragma unroll
    for (int n = 0; n < 4; ++n) rj[n] = rvec[j0 + n * 16 + lrow];

    // LDS pair-staging: [128 rows][16 lanes + pad->17] uint2 (17.4 KB overlays bufs)
    uint2* dp = (uint2*)smem_raw;
    __syncthreads();   // main-loop LDS reads complete before overwrite

    // stage: in-lane top2 over this lane's 4 cols, per (m,rr) row
    #pragma unroll
    for (int m = 0; m < 2; ++m)
        #pragma unroll
        for (int rr = 0; rr < 4; ++rr) {
            const int rl = wid * 32 + m * 16 + g * 4 + rr;   // local row
            const int i  = i0 + rl;
            unsigned m1 = 0u, m2 = 0u;
            #pragma unroll
            for (int n = 0; n < 4; ++n) {
                const int j = j0 + n * 16 + lrow;
                unsigned key = f32key(acc[m][n][rr] + rj[n], j);
                if (i == j) key = 0u;              // self-mask
                UPD2(m1, m2, key)
            }
            uint2 pr; pr.x = m1; pr.y = m2;
            dp[rl * 17 + lrow] = pr;
        }

    __syncthreads();

    // reduce: thread t<128 = row, stream 16 pairs -> top-2 of the 64-col group
    if (t < 128) {
        unsigned m1 = 0u, m2 = 0u;
        #pragma unroll
        for (int l = 0; l < 16; ++l) {
            const uint2 pr = dp[t * 17 + l];
            UPD2(m1, m2, pr.x) UPD2(m1, m2, pr.y)
        }
        uint2 st; st.x = m1; st.y = m2;
        *(uint2*)(cand + (size_t)(i0 + t) * 128 + (size_t)jt * 2) = st;
    }
}

// ---- fused top-k + gathered diffs + finalize (last block sums partials) ----
__global__ __launch_bounds__(256) void topk_diffs_kernel(
    const unsigned* __restrict__ cand, const float* __restrict__ proj,
    const double* __restrict__ p1, double* __restrict__ p2, double* __restrict__ p3,
    unsigned* __restrict__ cnt, float* __restrict__ out)
{
    __shared__ double bs1[4], bs2[4], dred[4];
    __shared__ int lastflag;
    const int t = threadIdx.x, lane = t & 63, w = t >> 6;
    const int b = blockIdx.x * 4 + w;
    const uint2 kk = *(const uint2*)(cand + (size_t)b * 128 + lane * 2);
    unsigned k0 = kk.x, k1 = kk.y;

    float s1 = 0.f, s2 = 0.f;
    float prev[8];

    for (int k = 0; k < NK; ++k) {
        unsigned bv = k0 > k1 ? k0 : k1;
        #pragma unroll
        for (int o = 1; o <= 32; o <<= 1)
            bv = max(bv, (unsigned)__shfl_xor((int)bv, o, 64));
        const int idx = 4095 - (int)(bv & 0xFFFu);   // winner column, all lanes

        // gather proj row idx; lane holds elems [lane*8, lane*8+8)
        const float* pp = proj + (size_t)idx * 512 + lane * 8;
        const f32x4 a0 = *(const f32x4*)pp;
        const f32x4 a1 = *(const f32x4*)(pp + 4);
        float cur[8] = {a0[0], a0[1], a0[2], a0[3], a1[0], a1[1], a1[2], a1[3]};
        if (k) {
            #pragma unroll
            for (int j = 0; j < 8; ++j) { const float d = cur[j] - prev[j]; s1 += d * d; }
        }
        if (lane < 63) {
            const f32x4 n0 = *(const f32x4*)(pp + 8);
            const f32x4 n1 = *(const f32x4*)(pp + 12);
            const float nxt[8] = {n0[0], n0[1], n0[2], n0[3], n1[0], n1[1], n1[2], n1[3]};
            #pragma unroll
            for (int j = 0; j < 8; ++j) { const float d = nxt[j] - cur[j]; s2 += d * d; }
        }
        #pragma unroll
        for (int j = 0; j < 8; ++j) prev[j] = cur[j];

        // invalidate winner (keys are unique)
        if (k0 == bv) k0 = 0u;
        if (k1 == bv) k1 = 0u;
    }

    #pragma unroll
    for (int o = 32; o > 0; o >>= 1) { s1 += __shfl_down(s1, o, 64); s2 += __shfl_down(s2, o, 64); }
    if (lane == 0) { bs1[w] = (double)s1; bs2[w] = (double)s2; }
    __syncthreads();
    if (t == 0) {
        p2[blockIdx.x] = bs1[0] + bs1[1] + bs1[2] + bs1[3];
        p3[blockIdx.x] = bs2[0] + bs2[1] + bs2[2] + bs2[3];
        __threadfence();                              // release partials
        lastflag = (atomicAdd(cnt, 1u) == 1023u);     // device-scope
    }
    __syncthreads();
    if (lastflag) {                                   // last block finalizes
        if (t == 0) *cnt = 0u;                        // re-arm for next call
        __threadfence();                              // acquire others' partials
        double v = 0.0;
        for (int i = t; i < 1024; i += 256)
            v += p1[i] * (1.0 / 2097152.0)
               + p2[i] * (1.0 / 31457280.0)
               + p3[i] * (1.0 / 33030144.0);
        #pragma unroll
        for (int o = 32; o > 0; o >>= 1) v += __shfl_down(v, o, 64);
        if (lane == 0) dred[w] = v;
        __syncthreads();
        if (t == 0) out[0] = (float)(dred[0] + dred[1] + dred[2] + dred[3]);
    }
}

extern "C" void kernel_launch(void* const* d_in, const int* in_sizes, int n_in,
                              void* d_out, int out_size, void* d_ws, size_t ws_size,
                              hipStream_t stream) {
    const float* x    = (const float*)d_in[0];
    const float* Wemb = (const float*)d_in[1];
    const float* bemb = (const float*)d_in[2];
    const float* Wp   = (const float*)d_in[3];
    const float* bp   = (const float*)d_in[4];
    float* out  = (float*)d_out;
    float* proj = out + 1;                       // x_rec_proj, B*S*F floats

    char* ws = (char*)d_ws;
    _Float16* X16 = (_Float16*)ws;                               // 4 MB
    _Float16* Y16 = (_Float16*)(ws + ((size_t)4 << 20));         // 4 MB
    unsigned* cand = (unsigned*)(ws + ((size_t)8 << 20));        // 2 MB (4096 x 128 keys)
    float*  rvec  = (float*)(ws + ((size_t)10 << 20));           // 16 KB
    double* p1    = (double*)(ws + ((size_t)10 << 20) + 65536);  // 8 KB
    double* p2    = p1 + 1024;                                   // 8 KB
    double* p3    = p2 + 1024;                                   // 8 KB
    unsigned* cnt = (unsigned*)(p3 + 1024);                      // 4 B

    prep_kernel<<<NB / 4, 256, 0, stream>>>(x, Wemb, bemb, Wp, bp, X16, Y16, proj, rvec, p1, cnt);
    attn_gemm_kernel<<<2048, 256, 0, stream>>>(X16, Y16, rvec, cand);
    topk_diffs_kernel<<<NB / 4, 256, 0, stream>>>(cand, proj, p1, p2, p3, cnt, out);
}

// Round 23
// 65.882 us; speedup vs baseline: 1.3111x; 1.3111x over previous
//
#include <hip/hip_runtime.h>
#include <math.h>

#define NB 4096   // batch
#define NS 64     // seq
#define NF 8      // feat
#define ND 64     // d_model
#define KL 512    // GEMM K = NS*NF (rank-8 trick)
#define NK 16     // top-k

typedef _Float16 half8 __attribute__((ext_vector_type(8)));
typedef float    f32x4 __attribute__((ext_vector_type(4)));

#define GLD16(src, dst) \
  __builtin_amdgcn_global_load_lds((const __attribute__((address_space(1))) void*)(src), \
                                   (__attribute__((address_space(3))) void*)(dst), 16, 0, 0)

#define WAITVM(N) asm volatile("s_waitcnt vmcnt(" #N ")" ::: "memory")

// packed candidate key: top-20 bits of sortable f32 | (4095 - col).
// u32 max == exact (value, lowest-col) order; key 0 = -inf sentinel.
__device__ __forceinline__ unsigned f32key(float v, int col) {
    const unsigned u = __float_as_uint(v);
    const unsigned s = ((int)u < 0) ? ~u : (u | 0x80000000u);
    return (s & 0xFFFFF000u) | (unsigned)(4095 - col);
}

// top-2 maintenance (M1 >= M2 invariant)
#define UPD2(M1, M2, K) { const unsigned k_ = (K); \
    if (k_ > M1) { M2 = M1; M1 = k_; } else if (k_ > M2) M2 = k_; }

// ---------------- block reduce helper ----------------
__device__ __forceinline__ float blk_reduce(float v, float* red) {
    #pragma unroll
    for (int o = 32; o > 0; o >>= 1) v += __shfl_down(v, o, 64);
    const int t = threadIdx.x;
    __syncthreads();
    if ((t & 63) == 0) red[t >> 6] = v;
    __syncthreads();
    float r = 0.f;
    if (t == 0) r = red[0] + red[1] + red[2] + red[3];
    return r;
}

// ---- prep (consts fused): X16=fp16(x), Y16=fp16(x@G), proj=x@M+c8,
//      r[b]=sum_s x.u, term1 partial -> p1[bid] ----
__global__ __launch_bounds__(256) void prep_kernel(
    const float* __restrict__ x, const float* __restrict__ Wemb,
    const float* __restrict__ bemb, const float* __restrict__ Wp,
    const float* __restrict__ bp,
    _Float16* __restrict__ X16, _Float16* __restrict__ Y16,
    float* __restrict__ proj, float* __restrict__ r, double* __restrict__ p1)
{
    __shared__ float sWe[512], sWp[512], sbe[64], sbp[8];
    __shared__ float sG[64], sM[64], su[8], sc[8];
    __shared__ float red[4];
    const int t = threadIdx.x, lane = t & 63, w = t >> 6;
    sWe[t] = Wemb[t]; sWe[t + 256] = Wemb[t + 256];
    sWp[t] = Wp[t];   sWp[t + 256] = Wp[t + 256];
    if (t < 64) sbe[t] = bemb[t];
    if (t < 8)  sbp[t] = bp[t];
    __syncthreads();
    if (t < 64) {               // G = We@We^T, M = We@Wp  (8x8 each)
        const int f = t >> 3, f2 = t & 7;
        float g = 0.f, m = 0.f;
        #pragma unroll
        for (int d = 0; d < ND; ++d) {
            g += sWe[f * ND + d] * sWe[f2 * ND + d];
            m += sWe[f * ND + d] * sWp[d * NF + f2];
        }
        sG[t] = g; sM[t] = m;
    }
    if (t < 8) {                // u = We@be, c8 = be@Wp + bp
        float uu = 0.f, cc = 0.f;
        #pragma unroll
        for (int d = 0; d < ND; ++d) {
            uu += sWe[t * ND + d] * sbe[d];
            cc += sbe[d] * sWp[d * NF + t];
        }
        su[t] = uu; sc[t] = cc + sbp[t];
    }
    __syncthreads();

    const int b = blockIdx.x * 4 + w;
    const size_t base = (size_t)b * KL + lane * 8;
    const f32x4 x0 = *(const f32x4*)&x[base];
    const f32x4 x1 = *(const f32x4*)&x[base + 4];
    float xv[8] = {x0[0], x0[1], x0[2], x0[3], x1[0], x1[1], x1[2], x1[3]};
    float yv[8], pv[8];
    #pragma unroll
    for (int f2 = 0; f2 < 8; ++f2) { yv[f2] = 0.f; pv[f2] = sc[f2]; }
    #pragma unroll
    for (int f = 0; f < 8; ++f)
        #pragma unroll
        for (int f2 = 0; f2 < 8; ++f2) {
            yv[f2] += xv[f] * sG[f * 8 + f2];
            pv[f2] += xv[f] * sM[f * 8 + f2];
        }
    half8 hx, hy;
    #pragma unroll
    for (int j = 0; j < 8; ++j) { hx[j] = (_Float16)xv[j]; hy[j] = (_Float16)yv[j]; }
    *(half8*)&X16[base] = hx;
    *(half8*)&Y16[base] = hy;
    *(f32x4*)&proj[base] = (f32x4){pv[0], pv[1], pv[2], pv[3]};
    *(f32x4*)&proj[base + 4] = (f32x4){pv[4], pv[5], pv[6], pv[7]};
    float rv = 0.f;
    #pragma unroll
    for (int f = 0; f < 8; ++f) rv += xv[f] * su[f];
    #pragma unroll
    for (int o = 32; o > 0; o >>= 1) rv += __shfl_down(rv, o, 64);
    if (lane == 0) r[b] = rv;
    float s1 = 0.f;
    #pragma unroll
    for (int j = 0; j < 8; ++j) { const float d = pv[j] - xv[j]; s1 += d * d; }
    const float tot = blk_reduce(s1, red);
    if (t == 0) p1[blockIdx.x] = (double)tot;
}

// ---- dot = X @ Y^T (K=512) fp16 MFMA, 128x64 tiles (2048 blocks),
//      BK=64 phases: 8 phases x (6 GLD16 + 16 MFMA + 1 barrier), 3-buf depth-2 ----
__global__ __launch_bounds__(256) void attn_gemm_kernel(
    const _Float16* __restrict__ Xf, const _Float16* __restrict__ Yf,
    const float* __restrict__ rvec, unsigned* __restrict__ cand)
{
    // 3 bufs x (A 128x64 = 16 KB + B 64x64 = 8 KB) = 72 KB; dp overlays (17.4 KB)
    __shared__ __align__(16) char smem_raw[73728];
    _Float16* smem = (_Float16*)smem_raw;

    const int t = threadIdx.x;
    const int lane = t & 63, wid = t >> 6;

    // 2D XCD map: each XCD owns an 8(it) x 32(jt) rectangle -> ~3 MB L2 working set
    const int xcd = blockIdx.x & 7, q = blockIdx.x >> 3;
    const int it = (xcd >> 1) * 8 + (q >> 5);       // 0..31
    const int jt = (xcd & 1) * 32 + (q & 31);       // 0..63
    const int i0 = it * 128, j0 = jt * 64;

    f32x4 acc[2][4];
    #pragma unroll
    for (int m = 0; m < 2; ++m)
        #pragma unroll
        for (int n = 0; n < 4; ++n) acc[m][n] = (f32x4){0.f, 0.f, 0.f, 0.f};

    const int lrow = lane & 15, g = lane >> 4;

    // staging: per stage 1536 chunks (A 1024: row=id>>3,c=id&7; B 512) ; 6/thread
    // source-side 3-bit XOR swizzle: global chunk = c ^ (row&7)
    const int idA0 = t,       rA0 = idA0 >> 3, cA0s = ((idA0 & 7) ^ (rA0 & 7)) * 8;
    const int idA1 = t + 256, rA1 = idA1 >> 3, cA1s = ((idA1 & 7) ^ (rA1 & 7)) * 8;
    const int idA2 = t + 512, rA2 = idA2 >> 3, cA2s = ((idA2 & 7) ^ (rA2 & 7)) * 8;
    const int idA3 = t + 768, rA3 = idA3 >> 3, cA3s = ((idA3 & 7) ^ (rA3 & 7)) * 8;
    const int idB0 = t,       rB0 = idB0 >> 3, cB0s = ((idB0 & 7) ^ (rB0 & 7)) * 8;
    const int idB1 = t + 256, rB1 = idB1 >> 3, cB1s = ((idB1 & 7) ^ (rB1 & 7)) * 8;
    const _Float16* pA0 = Xf + (size_t)(i0 + rA0) * KL + cA0s;
    const _Float16* pA1 = Xf + (size_t)(i0 + rA1) * KL + cA1s;
    const _Float16* pA2 = Xf + (size_t)(i0 + rA2) * KL + cA2s;
    const _Float16* pA3 = Xf + (size_t)(i0 + rA3) * KL + cA3s;
    const _Float16* pB0 = Yf + (size_t)(j0 + rB0) * KL + cB0s;
    const _Float16* pB1 = Yf + (size_t)(j0 + rB1) * KL + cB1s;
    _Float16* dA0 = smem + idA0 * 8;
    _Float16* dA1 = smem + idA1 * 8;
    _Float16* dA2 = smem + idA2 * 8;
    _Float16* dA3 = smem + idA3 * 8;
    _Float16* dB0 = smem + 8192 + idB0 * 8;   // B at +16 KB (8192 halves)
    _Float16* dB1 = smem + 8192 + idB1 * 8;

#define STG(BUF, KH) { \
    GLD16(pA0 + (KH), dA0 + (BUF) * 12288); \
    GLD16(pA1 + (KH), dA1 + (BUF) * 12288); \
    GLD16(pA2 + (KH), dA2 + (BUF) * 12288); \
    GLD16(pA3 + (KH), dA3 + (BUF) * 12288); \
    GLD16(pB0 + (KH), dB0 + (BUF) * 12288); \
    GLD16(pB1 + (KH), dB1 + (BUF) * 12288); }

    // read side: row stride 64 halves; chunk = (ks*4+g) ^ (lrow&7)
    const int swz0 = (g ^ (lrow & 7)) * 8;          // ks=0
    const int swz1 = ((4 + g) ^ (lrow & 7)) * 8;    // ks=1
    const int roA = (wid * 32 + lrow) * 64;         // wave's 32-row quarter
    const int roB = lrow * 64;

#define COMPUTE(BUF) { \
    const _Float16* sA = smem + (BUF) * 12288 + roA; \
    const _Float16* sB = smem + (BUF) * 12288 + 8192 + roB; \
    _Pragma("unroll") \
    for (int ks = 0; ks < 2; ++ks) { \
        const int sw = ks ? swz1 : swz0; \
        half8 fa[2], fb[4]; \
        _Pragma("unroll") \
        for (int m = 0; m < 2; ++m) fa[m] = *(const half8*)&sA[m * 1024 + sw]; \
        _Pragma("unroll") \
        for (int n = 0; n < 4; ++n) fb[n] = *(const half8*)&sB[n * 1024 + sw]; \
        _Pragma("unroll") \
        for (int m = 0; m < 2; ++m) \
            _Pragma("unroll") \
            for (int n = 0; n < 4; ++n) \
                acc[m][n] = __builtin_amdgcn_mfma_f32_16x16x32_f16(fa[m], fb[n], acc[m][n], 0, 0, 0); \
    } }

#define BUMP(NH) { pA0 += NH; pA1 += NH; pA2 += NH; pA3 += NH; pB0 += NH; pB1 += NH; }

    // prologue: stages 0 (k=0), 1 (k=64)
    STG(0, 0); STG(1, 64);
    BUMP(128)
    // phases 0..5: wait own stage, barrier, stage ph+2, compute
    #pragma unroll 1
    for (int io = 0; io < 2; ++io) {
        WAITVM(6); __builtin_amdgcn_s_barrier(); STG(2, 0);   COMPUTE(0);
        WAITVM(6); __builtin_amdgcn_s_barrier(); STG(0, 64);  COMPUTE(1);
        WAITVM(6); __builtin_amdgcn_s_barrier(); STG(1, 128); COMPUTE(2);
        BUMP(192)
    }
    // phases 6,7
    WAITVM(6); __builtin_amdgcn_s_barrier(); COMPUTE(0);
    WAITVM(0); __builtin_amdgcn_s_barrier(); COMPUTE(1);
#undef STG
#undef COMPUTE
#undef BUMP

    // r[j] for this lane's 4 cols (one per n-frag)
    float rj[4];
    #pragma unroll
    for (int n = 0; n < 4; ++n) rj[n] = rvec[j0 + n * 16 + lrow];

    // LDS pair-staging: [128 rows][16 lanes + pad->17] uint2 (17.4 KB overlays bufs)
    uint2* dp = (uint2*)smem_raw;
    __syncthreads();   // main-loop LDS reads complete before overwrite

    // stage: in-lane top2 over this lane's 4 cols, per (m,rr) row
    #pragma unroll
    for (int m = 0; m < 2; ++m)
        #pragma unroll
        for (int rr = 0; rr < 4; ++rr) {
            const int rl = wid * 32 + m * 16 + g * 4 + rr;   // local row
            const int i  = i0 + rl;
            unsigned m1 = 0u, m2 = 0u;
            #pragma unroll
            for (int n = 0; n < 4; ++n) {
                const int j = j0 + n * 16 + lrow;
                unsigned key = f32key(acc[m][n][rr] + rj[n], j);
                if (i == j) key = 0u;              // self-mask
                UPD2(m1, m2, key)
            }
            uint2 pr; pr.x = m1; pr.y = m2;
            dp[rl * 17 + lrow] = pr;
        }

    __syncthreads();

    // reduce: thread t<128 = row, stream 16 pairs -> top-2 of the 64-col group
    if (t < 128) {
        unsigned m1 = 0u, m2 = 0u;
        #pragma unroll
        for (int l = 0; l < 16; ++l) {
            const uint2 pr = dp[t * 17 + l];
            UPD2(m1, m2, pr.x) UPD2(m1, m2, pr.y)
        }
        uint2 st; st.x = m1; st.y = m2;
        *(uint2*)(cand + (size_t)(i0 + t) * 128 + (size_t)jt * 2) = st;
    }
}

// ---- fused top-k + gathered diffs: one wave per row, 2 candidate keys per lane;
//      per-block partial sums -> p2/p3[bid] ----
__global__ __launch_bounds__(256) void topk_diffs_kernel(
    const unsigned* __restrict__ cand, const float* __restrict__ proj,
    double* __restrict__ p2, double* __restrict__ p3)
{
    __shared__ double bs1[4], bs2[4];
    const int t = threadIdx.x, lane = t & 63, w = t >> 6;
    const int b = blockIdx.x * 4 + w;
    const uint2 kk = *(const uint2*)(cand + (size_t)b * 128 + lane * 2);
    unsigned k0 = kk.x, k1 = kk.y;

    float s1 = 0.f, s2 = 0.f;
    float prev[8];

    for (int k = 0; k < NK; ++k) {
        unsigned bv = k0 > k1 ? k0 : k1;
        #pragma unroll
        for (int o = 1; o <= 32; o <<= 1)
            bv = max(bv, (unsigned)__shfl_xor((int)bv, o, 64));
        const int idx = 4095 - (int)(bv & 0xFFFu);   // winner column, all lanes

        // gather proj row idx; lane holds elems [lane*8, lane*8+8)
        const float* pp = proj + (size_t)idx * 512 + lane * 8;
        const f32x4 a0 = *(const f32x4*)pp;
        const f32x4 a1 = *(const f32x4*)(pp + 4);
        float cur[8] = {a0[0], a0[1], a0[2], a0[3], a1[0], a1[1], a1[2], a1[3]};
        if (k) {
            #pragma unroll
            for (int j = 0; j < 8; ++j) { const float d = cur[j] - prev[j]; s1 += d * d; }
        }
        if (lane < 63) {
            const f32x4 n0 = *(const f32x4*)(pp + 8);
            const f32x4 n1 = *(const f32x4*)(pp + 12);
            const float nxt[8] = {n0[0], n0[1], n0[2], n0[3], n1[0], n1[1], n1[2], n1[3]};
            #pragma unroll
            for (int j = 0; j < 8; ++j) { const float d = nxt[j] - cur[j]; s2 += d * d; }
        }
        #pragma unroll
        for (int j = 0; j < 8; ++j) prev[j] = cur[j];

        // invalidate winner (keys are unique)
        if (k0 == bv) k0 = 0u;
        if (k1 == bv) k1 = 0u;
    }

    #pragma unroll
    for (int o = 32; o > 0; o >>= 1) { s1 += __shfl_down(s1, o, 64); s2 += __shfl_down(s2, o, 64); }
    if (lane == 0) { bs1[w] = (double)s1; bs2[w] = (double)s2; }
    __syncthreads();
    if (t == 0) {
        p2[blockIdx.x] = bs1[0] + bs1[1] + bs1[2] + bs1[3];
        p3[blockIdx.x] = bs2[0] + bs2[1] + bs2[2] + bs2[3];
    }
}

// ---------------- finalize: sum 3x1024 partials -> loss ----------------
__global__ __launch_bounds__(256) void finalize_kernel(
    const double* __restrict__ p1, const double* __restrict__ p2,
    const double* __restrict__ p3, float* __restrict__ out)
{
    __shared__ double dred[4];
    const int t = threadIdx.x, lane = t & 63, w = t >> 6;
    double v = 0.0;
    for (int i = t; i < 1024; i += 256)
        v += p1[i] * (1.0 / 2097152.0)
           + p2[i] * (1.0 / 31457280.0)
           + p3[i] * (1.0 / 33030144.0);
    #pragma unroll
    for (int o = 32; o > 0; o >>= 1) v += __shfl_down(v, o, 64);
    if (lane == 0) dred[w] = v;
    __syncthreads();
    if (t == 0) out[0] = (float)(dred[0] + dred[1] + dred[2] + dred[3]);
}

extern "C" void kernel_launch(void* const* d_in, const int* in_sizes, int n_in,
                              void* d_out, int out_size, void* d_ws, size_t ws_size,
                              hipStream_t stream) {
    const float* x    = (const float*)d_in[0];
    const float* Wemb = (const float*)d_in[1];
    const float* bemb = (const float*)d_in[2];
    const float* Wp   = (const float*)d_in[3];
    const float* bp   = (const float*)d_in[4];
    float* out  = (float*)d_out;
    float* proj = out + 1;                       // x_rec_proj, B*S*F floats

    char* ws = (char*)d_ws;
    _Float16* X16 = (_Float16*)ws;                               // 4 MB
    _Float16* Y16 = (_Float16*)(ws + ((size_t)4 << 20));         // 4 MB
    unsigned* cand = (unsigned*)(ws + ((size_t)8 << 20));        // 2 MB (4096 x 128 keys)
    float*  rvec  = (float*)(ws + ((size_t)10 << 20));           // 16 KB
    double* p1    = (double*)(ws + ((size_t)10 << 20) + 65536);  // 8 KB
    double* p2    = p1 + 1024;                                   // 8 KB
    double* p3    = p2 + 1024;                                   // 8 KB

    prep_kernel<<<NB / 4, 256, 0, stream>>>(x, Wemb, bemb, Wp, bp, X16, Y16, proj, rvec, p1);
    attn_gemm_kernel<<<2048, 256, 0, stream>>>(X16, Y16, rvec, cand);
    topk_diffs_kernel<<<NB / 4, 256, 0, stream>>>(cand, proj, p2, p3);
    finalize_kernel<<<1, 256, 0, stream>>>(p1, p2, p3, out);
}